// Round 7
// baseline (283.761 us; speedup 1.0000x reference)
//
#include <hip/hip_runtime.h>
#include <hip/hip_bf16.h>
#include <math.h>

#define N_SEQ 4096
#define D_MODEL 1024

typedef __attribute__((ext_vector_type(8))) short short8;
typedef __attribute__((ext_vector_type(16))) float f32x16;

__device__ __forceinline__ short f2bf(float f) {
  __hip_bfloat16 h = __float2bfloat16(f);
  return *reinterpret_cast<short*>(&h);
}
__device__ __forceinline__ float bf2f(short h) {
  return __uint_as_float(((unsigned)(unsigned short)h) << 16);
}

// async global->LDS, 16B per lane. LDS dest must be wave-uniform base + lane*16.
__device__ __forceinline__ void gload16(const short* g, short* l) {
  __builtin_amdgcn_global_load_lds(
      (const __attribute__((address_space(1))) void*)g,
      (__attribute__((address_space(3))) void*)l, 16, 0, 0);
}

// ---------------------------------------------------------------------------
// XOR-swizzled staging (NT threads): tile ROWS x 64 shorts. Slot s (16B):
// r = s>>3, c8 = (s&7)^(r&7) -> fragment ds_read_b128 hits all 32 banks
// (2-way, free). HL: row = [hi 32 | lo 32] shorts, K-step 32.
// ---------------------------------------------------------------------------
template <int ROWS, bool HL, int NT>
__device__ __forceinline__ void stage_sw(const short* __restrict__ hi,
                                         const short* __restrict__ lo, int ld,
                                         int r0, int k0, short* dst, int tid) {
#pragma unroll
  for (int i = 0; i < ROWS * 8 / NT; ++i) {
    const int s = i * NT + tid;
    const int r = s >> 3;
    const int c8 = (s & 7) ^ (r & 7);
    const short* src;
    int col;
    if (HL) {
      src = (c8 < 4) ? hi : lo;
      col = (c8 & 3) * 8;
    } else {
      src = hi;
      col = c8 * 8;
    }
    gload16(&src[(size_t)(r0 + r) * ld + k0 + col], &dst[s * 8]);
  }
}

// ---------------------------------------------------------------------------
// bf16 MFMA GEMM (NT layout), 128 x BN tile, 32x32x16 MFMA.
// NT=256: 4 waves 2x2, wave tile 64x64 (MI=NI=2 frags of 32).
// NT=512: 8 waves 4x2, wave tile 32x(BN/2) (MI=1, NI=BN/64).
// Operand layout (32x32x16): m/n = lane&31, k = (lane>>5)*8 + j.
// C/D layout (verified m74/m101): col=lane&31, row=(r&3)+8*(r>>2)+4*(lane>>5).
// HL: 3-product split-bf16 (fp32-grade): Ah*Bh + Ah*Bl + Al*Bh, KSTEP 32.
// OUT_MODE: 0 fp32, 1 bf16, 2 bf16 hi+lo split.
// MODE: 0 rect | 1 causal supertile-8 | 2 PV paired K-desc.
// K = k_base + k_per_mt*(rt0+mt).
// ---------------------------------------------------------------------------
template <bool HL, int OUT_MODE, int MODE, int BN, int NT, int MINW>
__global__ __launch_bounds__(NT, MINW)
void mfma_nt(const short* __restrict__ Ah, const short* __restrict__ Al,
             int lda, const short* __restrict__ Bh,
             const short* __restrict__ Bl, int ldb, void* __restrict__ C0,
             void* __restrict__ C1, int ldc, int out_row0, int rt0,
             int k_base, int k_per_mt) {
  constexpr int KSTEP = HL ? 32 : 64;
  constexpr int MI = (NT == 256) ? 2 : 1;
  constexpr int NI = (NT == 256) ? 2 : BN / 64;
  __shared__ short sA[128 * 64];
  __shared__ short sB[BN * 64];

  int mt, nt;
  if (MODE == 1) {
    // supertile-8 causal decode: super-rows R (mt in [8R,8R+8)), cum=32R^2+4R
    const int f = blockIdx.x;
    int R;
    if (f < 36) R = 0;
    else if (f < 136) R = 1;
    else if (f < 300) R = 2;
    else R = 3;
    const int rem = f - (32 * R * R + 4 * R);
    const int full = R << 6;
    if (rem < full) {
      const int C = rem >> 6, ww = rem & 63;
      mt = 8 * R + (ww >> 3);
      nt = 8 * C + (ww & 7);
    } else {
      const int d = rem - full;
      int lm = 0;
      while ((lm + 1) * (lm + 2) / 2 <= d) ++lm;
      mt = 8 * R + lm;
      nt = 8 * R + d - lm * (lm + 1) / 2;
    }
  } else if (MODE == 2) {
    const int t = (blockIdx.x < 256) ? (int)blockIdx.x : 767 - (int)blockIdx.x;
    mt = 31 - (t >> 4);
    nt = t & 15;
  } else {
    mt = blockIdx.y;
    nt = blockIdx.x;
  }
  const int m0 = mt * 128, n0 = nt * BN;
  const int K = k_base + k_per_mt * (rt0 + mt);

  const int tid = threadIdx.x;
  const int w = tid >> 6, lane = tid & 63;
  const int l31 = lane & 31, khalf = lane >> 5;  // k-base = khalf*8
  const int wm = (NT == 256) ? (w >> 1) * 64 : (w >> 1) * 32;
  const int wn = (w & 1) * (BN / 2);

  f32x16 acc[MI][NI];
#pragma unroll
  for (int mi = 0; mi < MI; ++mi)
#pragma unroll
    for (int ni = 0; ni < NI; ++ni)
#pragma unroll
      for (int r = 0; r < 16; ++r) acc[mi][ni][r] = 0.f;

  const int nk = K / KSTEP;
  for (int kt = 0; kt < nk; ++kt) {
    const int k0 = kt * KSTEP;
    stage_sw<128, HL, NT>(Ah, Al, lda, m0, k0, sA, tid);
    stage_sw<BN, HL, NT>(Bh, Bl, ldb, n0, k0, sB, tid);
    __syncthreads();
    if (HL) {
#pragma unroll
      for (int s = 0; s < 2; ++s) {  // two K=16 halves of KSTEP=32
        const int ch = s * 2 + khalf;  // hi chunk in [0,4)
        short8 ah[MI], al[MI], bh[NI], bl[NI];
#pragma unroll
        for (int mi = 0; mi < MI; ++mi) {
          const int rr = wm + mi * 32 + l31;
          ah[mi] = *(const short8*)&sA[rr * 64 + ((ch ^ (rr & 7)) << 3)];
          al[mi] = *(const short8*)&sA[rr * 64 + (((ch + 4) ^ (rr & 7)) << 3)];
        }
#pragma unroll
        for (int ni = 0; ni < NI; ++ni) {
          const int rr = wn + ni * 32 + l31;
          bh[ni] = *(const short8*)&sB[rr * 64 + ((ch ^ (rr & 7)) << 3)];
          bl[ni] = *(const short8*)&sB[rr * 64 + (((ch + 4) ^ (rr & 7)) << 3)];
        }
#pragma unroll
        for (int mi = 0; mi < MI; ++mi)
#pragma unroll
          for (int ni = 0; ni < NI; ++ni) {
            acc[mi][ni] = __builtin_amdgcn_mfma_f32_32x32x16_bf16(
                ah[mi], bh[ni], acc[mi][ni], 0, 0, 0);
            acc[mi][ni] = __builtin_amdgcn_mfma_f32_32x32x16_bf16(
                ah[mi], bl[ni], acc[mi][ni], 0, 0, 0);
            acc[mi][ni] = __builtin_amdgcn_mfma_f32_32x32x16_bf16(
                al[mi], bh[ni], acc[mi][ni], 0, 0, 0);
          }
      }
    } else {
#pragma unroll
      for (int kf = 0; kf < 4; ++kf) {  // four K=16 slices of KSTEP=64
        const int ch = kf * 2 + khalf;
        short8 ah[MI], bh[NI];
#pragma unroll
        for (int mi = 0; mi < MI; ++mi) {
          const int rr = wm + mi * 32 + l31;
          ah[mi] = *(const short8*)&sA[rr * 64 + ((ch ^ (rr & 7)) << 3)];
        }
#pragma unroll
        for (int ni = 0; ni < NI; ++ni) {
          const int rr = wn + ni * 32 + l31;
          bh[ni] = *(const short8*)&sB[rr * 64 + ((ch ^ (rr & 7)) << 3)];
        }
#pragma unroll
        for (int mi = 0; mi < MI; ++mi)
#pragma unroll
          for (int ni = 0; ni < NI; ++ni)
            acc[mi][ni] = __builtin_amdgcn_mfma_f32_32x32x16_bf16(
                ah[mi], bh[ni], acc[mi][ni], 0, 0, 0);
      }
    }
    __syncthreads();
  }

#pragma unroll
  for (int mi = 0; mi < MI; ++mi)
#pragma unroll
    for (int ni = 0; ni < NI; ++ni)
#pragma unroll
      for (int r = 0; r < 16; ++r) {
        const int row = out_row0 + m0 + wm + mi * 32 + (r & 3) + 8 * (r >> 2) +
                        4 * khalf;
        const int col = n0 + wn + ni * 32 + l31;
        const float v = acc[mi][ni][r];
        if (OUT_MODE == 0) {
          ((float*)C0)[(size_t)row * ldc + col] = v;
        } else if (OUT_MODE == 1) {
          ((short*)C0)[(size_t)row * ldc + col] = f2bf(v);
        } else {
          const short h = f2bf(v);
          ((short*)C0)[(size_t)row * ldc + col] = h;
          ((short*)C1)[(size_t)row * ldc + col] = f2bf(v - bf2f(h));
        }
      }
}

// ---------------------------------------------------------------------------
// Fused prep, flat grid of 1536 x 256 thr:
//  b < 1024: x 64x64 tile -> xh, xl (row-major) + xbT (hi transpose)
//  b < 1280: wqk tile -> wqkTh, wqkTl (transposed)
//  else    : wov tile -> wovT (transposed)
// ---------------------------------------------------------------------------
__global__ __launch_bounds__(256)
void prep_all(const float* __restrict__ x, const float* __restrict__ wqk,
              const float* __restrict__ wov, short* __restrict__ xh,
              short* __restrict__ xl, short* __restrict__ xbT,
              short* __restrict__ wqkTh, short* __restrict__ wqkTl,
              short* __restrict__ wovT) {
  __shared__ short Th[64][72];
  __shared__ short Tl[64][72];
  const int tid = threadIdx.x;
  const int b = blockIdx.x;

  const float* in;
  int r0, c0, C, R;
  bool do_lo, do_rowmajor;
  short *hiT, *loT;
  if (b < 1024) {
    in = x; R = N_SEQ; C = D_MODEL;
    r0 = (b & 63) * 64; c0 = (b >> 6) * 64;
    do_lo = true; do_rowmajor = true; hiT = xbT; loT = nullptr;
  } else if (b < 1280) {
    in = wqk; R = D_MODEL; C = D_MODEL;
    r0 = ((b - 1024) & 15) * 64; c0 = ((b - 1024) >> 4) * 64;
    do_lo = true; do_rowmajor = false; hiT = wqkTh; loT = wqkTl;
  } else {
    in = wov; R = D_MODEL; C = D_MODEL;
    r0 = ((b - 1280) & 15) * 64; c0 = ((b - 1280) >> 4) * 64;
    do_lo = false; do_rowmajor = false; hiT = wovT; loT = nullptr;
  }

#pragma unroll
  for (int i = 0; i < 4; ++i) {
    const int rr = (tid >> 4) + i * 16;
    const int cc = (tid & 15) * 4;
    const float4 v = *(const float4*)&in[(size_t)(r0 + rr) * C + c0 + cc];
    const float f[4] = {v.x, v.y, v.z, v.w};
    short h[4], l[4];
#pragma unroll
    for (int j = 0; j < 4; ++j) {
      h[j] = f2bf(f[j]);
      l[j] = do_lo ? f2bf(f[j] - bf2f(h[j])) : (short)0;
      Th[rr][cc + j] = h[j];
      Tl[rr][cc + j] = l[j];
    }
    if (do_rowmajor) {
      *(short4*)&xh[(size_t)(r0 + rr) * C + c0 + cc] =
          make_short4(h[0], h[1], h[2], h[3]);
      *(short4*)&xl[(size_t)(r0 + rr) * C + c0 + cc] =
          make_short4(l[0], l[1], l[2], l[3]);
    }
  }
  __syncthreads();
#pragma unroll
  for (int i = 0; i < 2; ++i) {
    const int idx = tid + i * 256;
    const int oc = idx >> 3;
    const int ch = (idx & 7) * 8;
    float4 u;
    short* t = (short*)&u;
#pragma unroll
    for (int j = 0; j < 8; ++j) t[j] = Th[ch + j][oc];
    *(float4*)&hiT[(size_t)(c0 + oc) * R + r0 + ch] = u;
    if (loT) {
#pragma unroll
      for (int j = 0; j < 8; ++j) t[j] = Tl[ch + j][oc];
      *(float4*)&loT[(size_t)(c0 + oc) * R + r0 + ch] = u;
    }
  }
}

// ---------------------------------------------------------------------------
// Row softmax, single pass, in place: S row (fp32) -> P bf16 over the same
// storage. Pads row gi to ((gi>>7)+1)*128. One block (256 thr) per row.
// ---------------------------------------------------------------------------
__global__ __launch_bounds__(256)
void softmax_inplace(float* __restrict__ S, int row0) {
  const int li = blockIdx.x;
  const int gi = row0 + li;
  const int valid = gi + 1;
  const int padded = ((gi >> 7) + 1) << 7;
  const int nf4 = padded >> 2;
  float* srow = S + (size_t)li * N_SEQ;
  short* prow = (short*)srow;
  const int tid = threadIdx.x;
  const int w = tid >> 6, lane = tid & 63;
  __shared__ float wred[4];
  __shared__ float sm, sil;

  float4 v[4];
  float m = -1e30f;
#pragma unroll
  for (int k = 0; k < 4; ++k) {
    const int j = tid + k * 256;
    if (j < nf4) {
      v[k] = ((const float4*)srow)[j];
      float* f = (float*)&v[k];
#pragma unroll
      for (int e = 0; e < 4; ++e)
        if (4 * j + e < valid) m = fmaxf(m, f[e]);
    }
  }
#pragma unroll
  for (int off = 32; off > 0; off >>= 1) m = fmaxf(m, __shfl_down(m, off));
  if (lane == 0) wred[w] = m;
  __syncthreads();
  if (tid == 0) sm = fmaxf(fmaxf(wred[0], wred[1]), fmaxf(wred[2], wred[3]));
  __syncthreads();
  m = sm;

  float l = 0.f;
#pragma unroll
  for (int k = 0; k < 4; ++k) {
    const int j = tid + k * 256;
    if (j < nf4) {
      float* f = (float*)&v[k];
#pragma unroll
      for (int e = 0; e < 4; ++e) {
        const float p = (4 * j + e < valid) ? __expf(f[e] - m) : 0.f;
        f[e] = p;
        l += p;
      }
    }
  }
#pragma unroll
  for (int off = 32; off > 0; off >>= 1) l += __shfl_down(l, off);
  if (lane == 0) wred[w] = l;
  __syncthreads();
  if (tid == 0) sil = 1.f / (wred[0] + wred[1] + wred[2] + wred[3]);
  __syncthreads();
  const float il = sil;

#pragma unroll
  for (int k = 0; k < 4; ++k) {
    const int j = tid + k * 256;
    if (j < nf4) {
      const float* f = (const float*)&v[k];
      *(short4*)&prow[4 * j] = make_short4(f2bf(f[0] * il), f2bf(f[1] * il),
                                           f2bf(f[2] * il), f2bf(f[3] * il));
    }
  }
}

// ---------------------------------------------------------------------------
extern "C" void kernel_launch(void* const* d_in, const int* in_sizes, int n_in,
                              void* d_out, int out_size, void* d_ws,
                              size_t ws_size, hipStream_t stream) {
  (void)in_sizes; (void)n_in; (void)out_size; (void)ws_size;
  const float* x   = (const float*)d_in[0];
  const float* wqk = (const float*)d_in[1];
  const float* wov = (const float*)d_in[2];
  float* out = (float*)d_out;

  const size_t MB = 1ull << 20;
  char* p = (char*)d_ws;
  short* xh    = (short*)(p);             //  8 MB 4096x1024 bf16 hi
  short* xl    = (short*)(p + 8 * MB);    //  8 MB           bf16 lo
  short* xbT   = (short*)(p + 16 * MB);   //  8 MB 1024x4096 bf16 hi^T
  short* wqkTh = (short*)(p + 24 * MB);   //  2 MB
  short* wqkTl = (short*)(p + 26 * MB);   //  2 MB
  short* wovT  = (short*)(p + 28 * MB);   //  2 MB
  short* ob    = (short*)(p + 30 * MB);   //  8 MB 4096x1024 bf16
  short* qh    = (short*)(p + 38 * MB);   //  8 MB
  short* ql    = (short*)(p + 46 * MB);   //  8 MB
  float* S     = (float*)(p + 54 * MB);   // 64 MB 4096x4096 fp32 (P aliases)
                                          // total 118 MB

  prep_all<<<1536, 256, 0, stream>>>(x, wqk, wov, xh, xl, xbT, wqkTh, wqkTl,
                                     wovT);
  // q = x @ wqk  (split-bf16 3-product, out split hi/lo; 512 thr)
  mfma_nt<true, 2, 0, 128, 512, 4><<<dim3(8, 32), 512, 0, stream>>>(
      xh, xl, 1024, wqkTh, wqkTl, 1024, qh, ql, 1024, 0, 0, D_MODEL, 0);
  // S = q @ x^T causal (256 thr, 64x64 wave tiles for LDS reuse; supertile-8)
  mfma_nt<true, 0, 1, 128, 256, 2><<<528, 256, 0, stream>>>(
      qh, ql, 1024, xh, xl, 1024, S, nullptr, N_SEQ, 0, 0, D_MODEL, 0);
  // softmax rows -> P bf16 in place
  softmax_inplace<<<N_SEQ, 256, 0, stream>>>(S, 0);
  // o = P @ x  (bf16; 128x64 tiles, K-desc order, balanced resident pairs)
  mfma_nt<false, 1, 2, 64, 512, 4><<<512, 512, 0, stream>>>(
      (const short*)S, nullptr, 8192, xbT, nullptr, N_SEQ,
      ob, nullptr, 1024, 0, 0, 128, 128);
  // out = o @ wov (bf16, fp32 out)
  mfma_nt<false, 0, 0, 128, 512, 4><<<dim3(8, 32), 512, 0, stream>>>(
      ob, nullptr, 1024, wovT, nullptr, 1024, out, nullptr, 1024, 0, 0,
      D_MODEL, 0);
}

// Round 8
// 267.459 us; speedup vs baseline: 1.0610x; 1.0610x over previous
//
#include <hip/hip_runtime.h>
#include <hip/hip_bf16.h>
#include <math.h>

#define N_SEQ 4096
#define D_MODEL 1024

typedef __attribute__((ext_vector_type(8))) short short8;
typedef __attribute__((ext_vector_type(4))) float f32x4;

__device__ __forceinline__ short f2bf(float f) {
  __hip_bfloat16 h = __float2bfloat16(f);
  return *reinterpret_cast<short*>(&h);
}
__device__ __forceinline__ float bf2f(short h) {
  return __uint_as_float(((unsigned)(unsigned short)h) << 16);
}

// async global->LDS, 16B per lane. LDS dest must be wave-uniform base + lane*16.
__device__ __forceinline__ void gload16(const short* g, short* l) {
  __builtin_amdgcn_global_load_lds(
      (const __attribute__((address_space(1))) void*)g,
      (__attribute__((address_space(3))) void*)l, 16, 0, 0);
}

// ---------------------------------------------------------------------------
// XOR-swizzled staging (NT threads): tile ROWS x 64 shorts. Slot s (16B):
// r = s>>3, c8 = (s&7)^(r&7) -> fragment ds_read_b128 hits all 32 banks
// (2-way, free — verified R4: conflicts 6.5e6 -> 0). HL: row = [hi 32 | lo 32].
// ---------------------------------------------------------------------------
template <int ROWS, bool HL, int NT>
__device__ __forceinline__ void stage_sw(const short* __restrict__ hi,
                                         const short* __restrict__ lo, int ld,
                                         int r0, int k0, short* dst, int tid) {
#pragma unroll
  for (int i = 0; i < ROWS * 8 / NT; ++i) {
    const int s = i * NT + tid;
    const int r = s >> 3;
    const int c8 = (s & 7) ^ (r & 7);
    const short* src;
    int col;
    if (HL) {
      src = (c8 < 4) ? hi : lo;
      col = (c8 & 3) * 8;
    } else {
      src = hi;
      col = c8 * 8;
    }
    gload16(&src[(size_t)(r0 + r) * ld + k0 + col], &dst[s * 8]);
  }
}

// ---------------------------------------------------------------------------
// bf16 MFMA GEMM (NT layout), 128 x BN tile, 16x16x32 MFMA (R6 shape —
// 32x32x16 regressed: 4-way LDS conflicts, R7 post-mortem).
// NT=256: 4 waves 2x2, wave tile 64x64 (MI=4, NI=4) — max LDS reuse.
// NT=512: 8 waves 4x2, wave tile 32x(BN/2) (MI=2) — max occupancy.
// HL: 3-product split-bf16 (fp32-grade): Ah*Bh + Ah*Bl + Al*Bh, KSTEP 32.
// OUT_MODE: 0 fp32, 1 bf16, 2 bf16 hi+lo split.
// MODE: 0 rect | 1 causal supertile-8 | 2 PV paired K-desc (balanced pairs).
// K = k_base + k_per_mt*(rt0+mt).
// ---------------------------------------------------------------------------
template <bool HL, int OUT_MODE, int MODE, int BN, int NT, int MINW>
__global__ __launch_bounds__(NT, MINW)
void mfma_nt(const short* __restrict__ Ah, const short* __restrict__ Al,
             int lda, const short* __restrict__ Bh,
             const short* __restrict__ Bl, int ldb, void* __restrict__ C0,
             void* __restrict__ C1, int ldc, int out_row0, int rt0,
             int k_base, int k_per_mt) {
  constexpr int KSTEP = HL ? 32 : 64;
  constexpr int MI = (NT == 256) ? 4 : 2;
  constexpr int NIv = (NT == 256) ? 4 : BN / 32;
  __shared__ short sA[128 * 64];
  __shared__ short sB[BN * 64];

  int mt, nt;
  if (MODE == 1) {
    // supertile-8 causal decode: super-rows R (mt in [8R,8R+8)), cum=32R^2+4R
    const int f = blockIdx.x;
    int R;
    if (f < 36) R = 0;
    else if (f < 136) R = 1;
    else if (f < 300) R = 2;
    else R = 3;
    const int rem = f - (32 * R * R + 4 * R);
    const int full = R << 6;
    if (rem < full) {
      const int C = rem >> 6, ww = rem & 63;
      mt = 8 * R + (ww >> 3);
      nt = 8 * C + (ww & 7);
    } else {
      const int d = rem - full;
      int lm = 0;
      while ((lm + 1) * (lm + 2) / 2 <= d) ++lm;
      mt = 8 * R + lm;
      nt = 8 * R + d - lm * (lm + 1) / 2;
    }
  } else if (MODE == 2) {
    const int t = (blockIdx.x < 256) ? (int)blockIdx.x : 767 - (int)blockIdx.x;
    mt = 31 - (t >> 4);
    nt = t & 15;
  } else {
    mt = blockIdx.y;
    nt = blockIdx.x;
  }
  const int m0 = mt * 128, n0 = nt * BN;
  const int K = k_base + k_per_mt * (rt0 + mt);

  const int tid = threadIdx.x;
  const int w = tid >> 6, lane = tid & 63;
  const int quad = lane >> 4, l15 = lane & 15;
  const int wm = (NT == 256) ? (w >> 1) * 64 : (w >> 1) * 32;
  const int wn = (w & 1) * (BN / 2);

  f32x4 acc[MI][NIv];
#pragma unroll
  for (int mi = 0; mi < MI; ++mi)
#pragma unroll
    for (int ni = 0; ni < NIv; ++ni)
#pragma unroll
      for (int r = 0; r < 4; ++r) acc[mi][ni][r] = 0.f;

  const int nk = K / KSTEP;
  for (int kt = 0; kt < nk; ++kt) {
    const int k0 = kt * KSTEP;
    stage_sw<128, HL, NT>(Ah, Al, lda, m0, k0, sA, tid);
    stage_sw<BN, HL, NT>(Bh, Bl, ldb, n0, k0, sB, tid);
    __syncthreads();
    if (HL) {
      short8 a[MI], am[MI], b[NIv], bm[NIv];
#pragma unroll
      for (int mi = 0; mi < MI; ++mi) {
        const int rr = wm + mi * 16 + l15;
        a[mi] = *(const short8*)&sA[rr * 64 + ((quad ^ (rr & 7)) << 3)];
        am[mi] = *(const short8*)&sA[rr * 64 + (((quad + 4) ^ (rr & 7)) << 3)];
      }
#pragma unroll
      for (int ni = 0; ni < NIv; ++ni) {
        const int rr = wn + ni * 16 + l15;
        b[ni] = *(const short8*)&sB[rr * 64 + ((quad ^ (rr & 7)) << 3)];
        bm[ni] = *(const short8*)&sB[rr * 64 + (((quad + 4) ^ (rr & 7)) << 3)];
      }
#pragma unroll
      for (int mi = 0; mi < MI; ++mi)
#pragma unroll
        for (int ni = 0; ni < NIv; ++ni) {
          acc[mi][ni] = __builtin_amdgcn_mfma_f32_16x16x32_bf16(
              a[mi], b[ni], acc[mi][ni], 0, 0, 0);
          acc[mi][ni] = __builtin_amdgcn_mfma_f32_16x16x32_bf16(
              a[mi], bm[ni], acc[mi][ni], 0, 0, 0);
          acc[mi][ni] = __builtin_amdgcn_mfma_f32_16x16x32_bf16(
              am[mi], b[ni], acc[mi][ni], 0, 0, 0);
        }
    } else {
#pragma unroll
      for (int s = 0; s < 2; ++s) {
        short8 a[MI], b[NIv];
#pragma unroll
        for (int mi = 0; mi < MI; ++mi) {
          const int rr = wm + mi * 16 + l15;
          a[mi] = *(const short8*)&sA[rr * 64 + (((s * 4 + quad) ^ (rr & 7)) << 3)];
        }
#pragma unroll
        for (int ni = 0; ni < NIv; ++ni) {
          const int rr = wn + ni * 16 + l15;
          b[ni] = *(const short8*)&sB[rr * 64 + (((s * 4 + quad) ^ (rr & 7)) << 3)];
        }
#pragma unroll
        for (int mi = 0; mi < MI; ++mi)
#pragma unroll
          for (int ni = 0; ni < NIv; ++ni)
            acc[mi][ni] = __builtin_amdgcn_mfma_f32_16x16x32_bf16(
                a[mi], b[ni], acc[mi][ni], 0, 0, 0);
      }
    }
    __syncthreads();
  }

#pragma unroll
  for (int mi = 0; mi < MI; ++mi)
#pragma unroll
    for (int ni = 0; ni < NIv; ++ni)
#pragma unroll
      for (int r = 0; r < 4; ++r) {
        const int row = out_row0 + m0 + wm + mi * 16 + quad * 4 + r;
        const int col = n0 + wn + ni * 16 + l15;
        const float v = acc[mi][ni][r];
        if (OUT_MODE == 0) {
          ((float*)C0)[(size_t)row * ldc + col] = v;
        } else if (OUT_MODE == 1) {
          ((short*)C0)[(size_t)row * ldc + col] = f2bf(v);
        } else {
          const short h = f2bf(v);
          ((short*)C0)[(size_t)row * ldc + col] = h;
          ((short*)C1)[(size_t)row * ldc + col] = f2bf(v - bf2f(h));
        }
      }
}

// ---------------------------------------------------------------------------
// Fused prep, flat grid of 4608 x 256 thr:
//  b < 4096: x elementwise split -> xh, xl (one float4/thread; no transpose
//            needed anymore — PV uses vT, not x^T)
//  b < 4352: wqk 64x64 tile -> wqkTh, wqkTl (transposed, hi+lo)
//  else    : wov tile -> wovT (transposed)
// ---------------------------------------------------------------------------
__global__ __launch_bounds__(256)
void prep_all(const float* __restrict__ x, const float* __restrict__ wqk,
              const float* __restrict__ wov, short* __restrict__ xh,
              short* __restrict__ xl, short* __restrict__ wqkTh,
              short* __restrict__ wqkTl, short* __restrict__ wovT) {
  __shared__ short Th[64][72];
  __shared__ short Tl[64][72];
  const int tid = threadIdx.x;
  const int b = blockIdx.x;

  if (b < 4096) {
    const int idx = b * 256 + tid;
    const float4 v = ((const float4*)x)[idx];
    const float f[4] = {v.x, v.y, v.z, v.w};
    short h[4], l[4];
#pragma unroll
    for (int i = 0; i < 4; ++i) {
      h[i] = f2bf(f[i]);
      l[i] = f2bf(f[i] - bf2f(h[i]));
    }
    ((short4*)xh)[idx] = make_short4(h[0], h[1], h[2], h[3]);
    ((short4*)xl)[idx] = make_short4(l[0], l[1], l[2], l[3]);
    return;
  }

  const bool is_qk = (b < 4352);
  const int local = b - (is_qk ? 4096 : 4352);
  const float* in = is_qk ? wqk : wov;
  short* hiT = is_qk ? wqkTh : wovT;
  short* loT = is_qk ? wqkTl : nullptr;
  const int r0 = (local & 15) * 64, c0 = (local >> 4) * 64;

#pragma unroll
  for (int i = 0; i < 4; ++i) {
    const int rr = (tid >> 4) + i * 16;
    const int cc = (tid & 15) * 4;
    const float4 v = *(const float4*)&in[(size_t)(r0 + rr) * D_MODEL + c0 + cc];
    const float f[4] = {v.x, v.y, v.z, v.w};
#pragma unroll
    for (int j = 0; j < 4; ++j) {
      const short h = f2bf(f[j]);
      Th[rr][cc + j] = h;
      Tl[rr][cc + j] = is_qk ? f2bf(f[j] - bf2f(h)) : (short)0;
    }
  }
  __syncthreads();
#pragma unroll
  for (int i = 0; i < 2; ++i) {
    const int idx = tid + i * 256;
    const int oc = idx >> 3;
    const int ch = (idx & 7) * 8;
    float4 u;
    short* t = (short*)&u;
#pragma unroll
    for (int j = 0; j < 8; ++j) t[j] = Th[ch + j][oc];
    *(float4*)&hiT[(size_t)(c0 + oc) * D_MODEL + r0 + ch] = u;
    if (loT) {
#pragma unroll
      for (int j = 0; j < 8; ++j) t[j] = Tl[ch + j][oc];
      *(float4*)&loT[(size_t)(c0 + oc) * D_MODEL + r0 + ch] = u;
    }
  }
}

// ---------------------------------------------------------------------------
// Row softmax, single pass, in place: S row (fp32) -> P bf16 over the same
// storage. Pads row gi to ((gi>>7)+1)*128 (== PV K for the row's m-tile).
// ---------------------------------------------------------------------------
__global__ __launch_bounds__(256)
void softmax_inplace(float* __restrict__ S, int row0) {
  const int li = blockIdx.x;
  const int gi = row0 + li;
  const int valid = gi + 1;
  const int padded = ((gi >> 7) + 1) << 7;
  const int nf4 = padded >> 2;
  float* srow = S + (size_t)li * N_SEQ;
  short* prow = (short*)srow;
  const int tid = threadIdx.x;
  const int w = tid >> 6, lane = tid & 63;
  __shared__ float wred[4];
  __shared__ float sm, sil;

  float4 v[4];
  float m = -1e30f;
#pragma unroll
  for (int k = 0; k < 4; ++k) {
    const int j = tid + k * 256;
    if (j < nf4) {
      v[k] = ((const float4*)srow)[j];
      float* f = (float*)&v[k];
#pragma unroll
      for (int e = 0; e < 4; ++e)
        if (4 * j + e < valid) m = fmaxf(m, f[e]);
    }
  }
#pragma unroll
  for (int off = 32; off > 0; off >>= 1) m = fmaxf(m, __shfl_down(m, off));
  if (lane == 0) wred[w] = m;
  __syncthreads();
  if (tid == 0) sm = fmaxf(fmaxf(wred[0], wred[1]), fmaxf(wred[2], wred[3]));
  __syncthreads();
  m = sm;

  float l = 0.f;
#pragma unroll
  for (int k = 0; k < 4; ++k) {
    const int j = tid + k * 256;
    if (j < nf4) {
      float* f = (float*)&v[k];
#pragma unroll
      for (int e = 0; e < 4; ++e) {
        const float p = (4 * j + e < valid) ? __expf(f[e] - m) : 0.f;
        f[e] = p;
        l += p;
      }
    }
  }
#pragma unroll
  for (int off = 32; off > 0; off >>= 1) l += __shfl_down(l, off);
  if (lane == 0) wred[w] = l;
  __syncthreads();
  if (tid == 0) sil = 1.f / (wred[0] + wred[1] + wred[2] + wred[3]);
  __syncthreads();
  const float il = sil;

#pragma unroll
  for (int k = 0; k < 4; ++k) {
    const int j = tid + k * 256;
    if (j < nf4) {
      const float* f = (const float*)&v[k];
      *(short4*)&prow[4 * j] = make_short4(f2bf(f[0] * il), f2bf(f[1] * il),
                                           f2bf(f[2] * il), f2bf(f[3] * il));
    }
  }
}

// ---------------------------------------------------------------------------
extern "C" void kernel_launch(void* const* d_in, const int* in_sizes, int n_in,
                              void* d_out, int out_size, void* d_ws,
                              size_t ws_size, hipStream_t stream) {
  (void)in_sizes; (void)n_in; (void)out_size; (void)ws_size;
  const float* x   = (const float*)d_in[0];
  const float* wqk = (const float*)d_in[1];
  const float* wov = (const float*)d_in[2];
  float* out = (float*)d_out;

  const size_t MB = 1ull << 20;
  char* p = (char*)d_ws;
  short* xh    = (short*)(p);             //  8 MB 4096x1024 bf16 hi
  short* xl    = (short*)(p + 8 * MB);    //  8 MB           bf16 lo
  short* wqkTh = (short*)(p + 16 * MB);   //  2 MB
  short* wqkTl = (short*)(p + 18 * MB);   //  2 MB
  short* wovT  = (short*)(p + 20 * MB);   //  2 MB
  short* qh    = (short*)(p + 22 * MB);   //  8 MB
  short* ql    = (short*)(p + 30 * MB);   //  8 MB
  short* vT    = (short*)(p + 38 * MB);   //  8 MB 1024x4096: vT[d][s]=(x@wov)[s][d]
  float* S     = (float*)(p + 46 * MB);   // 64 MB 4096x4096 fp32 (P aliases)
                                          // total 110 MB

  prep_all<<<4608, 256, 0, stream>>>(x, wqk, wov, xh, xl, wqkTh, wqkTl, wovT);
  // q = x @ wqk  (split-bf16 3-product, out split hi/lo; 512 thr)
  mfma_nt<true, 2, 0, 128, 512, 4><<<dim3(8, 32), 512, 0, stream>>>(
      xh, xl, 1024, wqkTh, wqkTl, 1024, qh, ql, 1024, 0, 0, D_MODEL, 0);
  // vT = (x @ wov)^T via NT GEMM: C[m][n] = sum_d wovT[m][d] * x[n][d]
  mfma_nt<false, 1, 0, 128, 512, 4><<<dim3(32, 8), 512, 0, stream>>>(
      wovT, nullptr, 1024, xh, nullptr, 1024, vT, nullptr, N_SEQ, 0, 0,
      D_MODEL, 0);
  // S = q @ x^T causal (256 thr, 64x64 wave tiles for LDS reuse; supertile-8)
  mfma_nt<true, 0, 1, 128, 256, 2><<<528, 256, 0, stream>>>(
      qh, ql, 1024, xh, xl, 1024, S, nullptr, N_SEQ, 0, 0, D_MODEL, 0);
  // softmax rows -> P bf16 in place
  softmax_inplace<<<N_SEQ, 256, 0, stream>>>(S, 0);
  // out = P @ v  (bf16 x bf16 -> fp32 out directly; 128x64 tiles, K-desc
  // paired order; B = vT so K (seq) is contiguous)
  mfma_nt<false, 0, 2, 64, 512, 4><<<512, 512, 0, stream>>>(
      (const short*)S, nullptr, 8192, vT, nullptr, N_SEQ,
      out, nullptr, 1024, 0, 0, 128, 128);
}

// Round 9
// 251.178 us; speedup vs baseline: 1.1297x; 1.0648x over previous
//
#include <hip/hip_runtime.h>
#include <hip/hip_bf16.h>
#include <math.h>

#define N_SEQ 4096
#define D_MODEL 1024

typedef __attribute__((ext_vector_type(8))) short short8;
typedef __attribute__((ext_vector_type(4))) float f32x4;

__device__ __forceinline__ short f2bf(float f) {
  __hip_bfloat16 h = __float2bfloat16(f);
  return *reinterpret_cast<short*>(&h);
}
__device__ __forceinline__ float bf2f(short h) {
  return __uint_as_float(((unsigned)(unsigned short)h) << 16);
}

// async global->LDS, 16B per lane. LDS dest must be wave-uniform base + lane*16.
__device__ __forceinline__ void gload16(const short* g, short* l) {
  __builtin_amdgcn_global_load_lds(
      (const __attribute__((address_space(1))) void*)g,
      (__attribute__((address_space(3))) void*)l, 16, 0, 0);
}

// ---------------------------------------------------------------------------
// XOR-swizzled staging (NT threads): tile ROWS x 64 shorts. Slot s (16B):
// r = s>>3, c8 = (s&7)^(r&7) -> fragment ds_read_b128 hits all 32 banks
// (2-way, free — verified R4: conflicts 6.5e6 -> 0). HL: row = [hi 32 | lo 32].
// ---------------------------------------------------------------------------
template <int ROWS, bool HL, int NT>
__device__ __forceinline__ void stage_sw(const short* __restrict__ hi,
                                         const short* __restrict__ lo, int ld,
                                         int r0, int k0, short* dst, int tid) {
#pragma unroll
  for (int i = 0; i < ROWS * 8 / NT; ++i) {
    const int s = i * NT + tid;
    const int r = s >> 3;
    const int c8 = (s & 7) ^ (r & 7);
    const short* src;
    int col;
    if (HL) {
      src = (c8 < 4) ? hi : lo;
      col = (c8 & 3) * 8;
    } else {
      src = hi;
      col = c8 * 8;
    }
    gload16(&src[(size_t)(r0 + r) * ld + k0 + col], &dst[s * 8]);
  }
}

// HL inner step (KSTEP=32): MI x NIv wave tile, 3-product split-bf16.
template <int MI, int NIv>
__device__ __forceinline__ void hl_step(const short* sA, const short* sB,
                                        int wm, int wn, int quad, int l15,
                                        f32x4 acc[MI][NIv]) {
  short8 a[MI], am[MI], b[NIv], bm[NIv];
#pragma unroll
  for (int mi = 0; mi < MI; ++mi) {
    const int rr = wm + mi * 16 + l15;
    a[mi] = *(const short8*)&sA[rr * 64 + ((quad ^ (rr & 7)) << 3)];
    am[mi] = *(const short8*)&sA[rr * 64 + (((quad + 4) ^ (rr & 7)) << 3)];
  }
#pragma unroll
  for (int ni = 0; ni < NIv; ++ni) {
    const int rr = wn + ni * 16 + l15;
    b[ni] = *(const short8*)&sB[rr * 64 + ((quad ^ (rr & 7)) << 3)];
    bm[ni] = *(const short8*)&sB[rr * 64 + (((quad + 4) ^ (rr & 7)) << 3)];
  }
#pragma unroll
  for (int mi = 0; mi < MI; ++mi)
#pragma unroll
    for (int ni = 0; ni < NIv; ++ni) {
      acc[mi][ni] = __builtin_amdgcn_mfma_f32_16x16x32_bf16(a[mi], b[ni],
                                                            acc[mi][ni], 0, 0, 0);
      acc[mi][ni] = __builtin_amdgcn_mfma_f32_16x16x32_bf16(a[mi], bm[ni],
                                                            acc[mi][ni], 0, 0, 0);
      acc[mi][ni] = __builtin_amdgcn_mfma_f32_16x16x32_bf16(am[mi], b[ni],
                                                            acc[mi][ni], 0, 0, 0);
    }
}

// non-HL inner step (KSTEP=64): two k=32 slices.
template <int MI, int NIv>
__device__ __forceinline__ void bf_step(const short* sA, const short* sB,
                                        int wm, int wn, int quad, int l15,
                                        f32x4 acc[MI][NIv]) {
#pragma unroll
  for (int s = 0; s < 2; ++s) {
    short8 a[MI], b[NIv];
#pragma unroll
    for (int mi = 0; mi < MI; ++mi) {
      const int rr = wm + mi * 16 + l15;
      a[mi] = *(const short8*)&sA[rr * 64 + (((s * 4 + quad) ^ (rr & 7)) << 3)];
    }
#pragma unroll
    for (int ni = 0; ni < NIv; ++ni) {
      const int rr = wn + ni * 16 + l15;
      b[ni] = *(const short8*)&sB[rr * 64 + (((s * 4 + quad) ^ (rr & 7)) << 3)];
    }
#pragma unroll
    for (int mi = 0; mi < MI; ++mi)
#pragma unroll
      for (int ni = 0; ni < NIv; ++ni)
        acc[mi][ni] = __builtin_amdgcn_mfma_f32_16x16x32_bf16(
            a[mi], b[ni], acc[mi][ni], 0, 0, 0);
  }
}

// ---------------------------------------------------------------------------
// Fused QK + vT dispatch, 784 blocks x 256 thr (4 waves, 64x64 wave tiles):
//  blocks [0,528): S = q @ x^T causal (supertile-8 order, split-bf16, fp32 out)
//  blocks [528,784): vT = (x @ wov)^T rect NT GEMM (bf16 out, ldc 4096)
// vT is independent of QK — its MFMA fills QK's barrier/vmcnt drains (m114).
// ---------------------------------------------------------------------------
__global__ __launch_bounds__(256, 2)
void fused_qk_v(const short* __restrict__ qh, const short* __restrict__ ql,
                const short* __restrict__ xh, const short* __restrict__ xl,
                const short* __restrict__ wovT, float* __restrict__ S,
                short* __restrict__ vT) {
  __shared__ short sA[128 * 64];
  __shared__ short sB[128 * 64];
  const int tid = threadIdx.x;
  const int w = tid >> 6, lane = tid & 63;
  const int quad = lane >> 4, l15 = lane & 15;
  const int wm = (w >> 1) * 64, wn = (w & 1) * 64;

  f32x4 acc[4][4];
#pragma unroll
  for (int mi = 0; mi < 4; ++mi)
#pragma unroll
    for (int ni = 0; ni < 4; ++ni)
#pragma unroll
      for (int r = 0; r < 4; ++r) acc[mi][ni][r] = 0.f;

  if (blockIdx.x < 528) {
    // ---- QK causal, supertile-8 decode ----
    const int f = blockIdx.x;
    int R;
    if (f < 36) R = 0;
    else if (f < 136) R = 1;
    else if (f < 300) R = 2;
    else R = 3;
    const int rem = f - (32 * R * R + 4 * R);
    const int full = R << 6;
    int mt, nt;
    if (rem < full) {
      const int C = rem >> 6, ww = rem & 63;
      mt = 8 * R + (ww >> 3);
      nt = 8 * C + (ww & 7);
    } else {
      const int d = rem - full;
      int lm = 0;
      while ((lm + 1) * (lm + 2) / 2 <= d) ++lm;
      mt = 8 * R + lm;
      nt = 8 * R + d - lm * (lm + 1) / 2;
    }
    const int m0 = mt * 128, n0 = nt * 128;
    for (int kt = 0; kt < 32; ++kt) {
      const int k0 = kt * 32;
      stage_sw<128, true, 256>(qh, ql, 1024, m0, k0, sA, tid);
      stage_sw<128, true, 256>(xh, xl, 1024, n0, k0, sB, tid);
      __syncthreads();
      hl_step<4, 4>(sA, sB, wm, wn, quad, l15, acc);
      __syncthreads();
    }
#pragma unroll
    for (int mi = 0; mi < 4; ++mi)
#pragma unroll
      for (int ni = 0; ni < 4; ++ni)
#pragma unroll
        for (int r = 0; r < 4; ++r) {
          const int row = m0 + wm + mi * 16 + quad * 4 + r;
          const int col = n0 + wn + ni * 16 + l15;
          S[(size_t)row * N_SEQ + col] = acc[mi][ni][r];
        }
  } else {
    // ---- vT = (x @ wov)^T : C[m][n] = sum_d wovT[m][d] * xh[n][d] ----
    const int f2 = blockIdx.x - 528;
    const int mt = f2 >> 5, nt = f2 & 31;
    const int m0 = mt * 128, n0 = nt * 128;
    for (int kt = 0; kt < 16; ++kt) {
      const int k0 = kt * 64;
      stage_sw<128, false, 256>(wovT, nullptr, 1024, m0, k0, sA, tid);
      stage_sw<128, false, 256>(xh, nullptr, 1024, n0, k0, sB, tid);
      __syncthreads();
      bf_step<4, 4>(sA, sB, wm, wn, quad, l15, acc);
      __syncthreads();
    }
#pragma unroll
    for (int mi = 0; mi < 4; ++mi)
#pragma unroll
      for (int ni = 0; ni < 4; ++ni)
#pragma unroll
        for (int r = 0; r < 4; ++r) {
          const int row = m0 + wm + mi * 16 + quad * 4 + r;
          const int col = n0 + wn + ni * 16 + l15;
          vT[(size_t)row * N_SEQ + col] = f2bf(acc[mi][ni][r]);
        }
  }
}

// ---------------------------------------------------------------------------
// bf16 MFMA GEMM (NT layout), 128 x BN tile, 16x16x32 MFMA.
// NT=256: 4 waves 2x2, wave tile 64x(BN/2) (MI=4, NIv=BN/32).
// NT=512: 8 waves 4x2, wave tile 32x(BN/2) (MI=2, NIv=BN/32).
// HL: 3-product split-bf16. OUT_MODE: 0 fp32, 1 bf16, 2 split hi/lo.
// MODE: 0 rect | 2 PV paired K-desc. K = k_base + k_per_mt*(rt0+mt).
// ---------------------------------------------------------------------------
template <bool HL, int OUT_MODE, int MODE, int BN, int NT, int MINW>
__global__ __launch_bounds__(NT, MINW)
void mfma_nt(const short* __restrict__ Ah, const short* __restrict__ Al,
             int lda, const short* __restrict__ Bh,
             const short* __restrict__ Bl, int ldb, void* __restrict__ C0,
             void* __restrict__ C1, int ldc, int out_row0, int rt0,
             int k_base, int k_per_mt) {
  constexpr int KSTEP = HL ? 32 : 64;
  constexpr int MI = (NT == 256) ? 4 : 2;
  constexpr int NIv = BN / 32;
  __shared__ short sA[128 * 64];
  __shared__ short sB[BN * 64];

  int mt, nt;
  if (MODE == 2) {
    const int t = (blockIdx.x < 256) ? (int)blockIdx.x : 767 - (int)blockIdx.x;
    mt = 31 - (t >> 4);
    nt = t & 15;
  } else {
    mt = blockIdx.y;
    nt = blockIdx.x;
  }
  const int m0 = mt * 128, n0 = nt * BN;
  const int K = k_base + k_per_mt * (rt0 + mt);

  const int tid = threadIdx.x;
  const int w = tid >> 6, lane = tid & 63;
  const int quad = lane >> 4, l15 = lane & 15;
  const int wm = (NT == 256) ? (w >> 1) * 64 : (w >> 1) * 32;
  const int wn = (w & 1) * (BN / 2);

  f32x4 acc[MI][NIv];
#pragma unroll
  for (int mi = 0; mi < MI; ++mi)
#pragma unroll
    for (int ni = 0; ni < NIv; ++ni)
#pragma unroll
      for (int r = 0; r < 4; ++r) acc[mi][ni][r] = 0.f;

  const int nk = K / KSTEP;
  for (int kt = 0; kt < nk; ++kt) {
    const int k0 = kt * KSTEP;
    stage_sw<128, HL, NT>(Ah, Al, lda, m0, k0, sA, tid);
    stage_sw<BN, HL, NT>(Bh, Bl, ldb, n0, k0, sB, tid);
    __syncthreads();
    if (HL)
      hl_step<MI, NIv>(sA, sB, wm, wn, quad, l15, acc);
    else
      bf_step<MI, NIv>(sA, sB, wm, wn, quad, l15, acc);
    __syncthreads();
  }

#pragma unroll
  for (int mi = 0; mi < MI; ++mi)
#pragma unroll
    for (int ni = 0; ni < NIv; ++ni)
#pragma unroll
      for (int r = 0; r < 4; ++r) {
        const int row = out_row0 + m0 + wm + mi * 16 + quad * 4 + r;
        const int col = n0 + wn + ni * 16 + l15;
        const float v = acc[mi][ni][r];
        if (OUT_MODE == 0) {
          ((float*)C0)[(size_t)row * ldc + col] = v;
        } else if (OUT_MODE == 1) {
          ((short*)C0)[(size_t)row * ldc + col] = f2bf(v);
        } else {
          const short h = f2bf(v);
          ((short*)C0)[(size_t)row * ldc + col] = h;
          ((short*)C1)[(size_t)row * ldc + col] = f2bf(v - bf2f(h));
        }
      }
}

// ---------------------------------------------------------------------------
// Fused prep, flat grid of 4608 x 256 thr:
//  b < 4096: x elementwise split -> xh, xl
//  b < 4352: wqk 64x64 tile -> wqkTh, wqkTl (transposed, hi+lo)
//  else    : wov tile -> wovT (transposed)
// ---------------------------------------------------------------------------
__global__ __launch_bounds__(256)
void prep_all(const float* __restrict__ x, const float* __restrict__ wqk,
              const float* __restrict__ wov, short* __restrict__ xh,
              short* __restrict__ xl, short* __restrict__ wqkTh,
              short* __restrict__ wqkTl, short* __restrict__ wovT) {
  __shared__ short Th[64][72];
  __shared__ short Tl[64][72];
  const int tid = threadIdx.x;
  const int b = blockIdx.x;

  if (b < 4096) {
    const int idx = b * 256 + tid;
    const float4 v = ((const float4*)x)[idx];
    const float f[4] = {v.x, v.y, v.z, v.w};
    short h[4], l[4];
#pragma unroll
    for (int i = 0; i < 4; ++i) {
      h[i] = f2bf(f[i]);
      l[i] = f2bf(f[i] - bf2f(h[i]));
    }
    ((short4*)xh)[idx] = make_short4(h[0], h[1], h[2], h[3]);
    ((short4*)xl)[idx] = make_short4(l[0], l[1], l[2], l[3]);
    return;
  }

  const bool is_qk = (b < 4352);
  const int local = b - (is_qk ? 4096 : 4352);
  const float* in = is_qk ? wqk : wov;
  short* hiT = is_qk ? wqkTh : wovT;
  short* loT = is_qk ? wqkTl : nullptr;
  const int r0 = (local & 15) * 64, c0 = (local >> 4) * 64;

#pragma unroll
  for (int i = 0; i < 4; ++i) {
    const int rr = (tid >> 4) + i * 16;
    const int cc = (tid & 15) * 4;
    const float4 v = *(const float4*)&in[(size_t)(r0 + rr) * D_MODEL + c0 + cc];
    const float f[4] = {v.x, v.y, v.z, v.w};
#pragma unroll
    for (int j = 0; j < 4; ++j) {
      const short h = f2bf(f[j]);
      Th[rr][cc + j] = h;
      Tl[rr][cc + j] = is_qk ? f2bf(f[j] - bf2f(h)) : (short)0;
    }
  }
  __syncthreads();
#pragma unroll
  for (int i = 0; i < 2; ++i) {
    const int idx = tid + i * 256;
    const int oc = idx >> 3;
    const int ch = (idx & 7) * 8;
    float4 u;
    short* t = (short*)&u;
#pragma unroll
    for (int j = 0; j < 8; ++j) t[j] = Th[ch + j][oc];
    *(float4*)&hiT[(size_t)(c0 + oc) * D_MODEL + r0 + ch] = u;
    if (loT) {
#pragma unroll
      for (int j = 0; j < 8; ++j) t[j] = Tl[ch + j][oc];
      *(float4*)&loT[(size_t)(c0 + oc) * D_MODEL + r0 + ch] = u;
    }
  }
}

// ---------------------------------------------------------------------------
// Row softmax, single pass, in place: S row (fp32) -> P bf16 over the same
// storage. Pads row gi to ((gi>>7)+1)*128 (== PV K for the row's m-tile).
// ---------------------------------------------------------------------------
__global__ __launch_bounds__(256)
void softmax_inplace(float* __restrict__ S, int row0) {
  const int li = blockIdx.x;
  const int gi = row0 + li;
  const int valid = gi + 1;
  const int padded = ((gi >> 7) + 1) << 7;
  const int nf4 = padded >> 2;
  float* srow = S + (size_t)li * N_SEQ;
  short* prow = (short*)srow;
  const int tid = threadIdx.x;
  const int w = tid >> 6, lane = tid & 63;
  __shared__ float wred[4];
  __shared__ float sm, sil;

  float4 v[4];
  float m = -1e30f;
#pragma unroll
  for (int k = 0; k < 4; ++k) {
    const int j = tid + k * 256;
    if (j < nf4) {
      v[k] = ((const float4*)srow)[j];
      float* f = (float*)&v[k];
#pragma unroll
      for (int e = 0; e < 4; ++e)
        if (4 * j + e < valid) m = fmaxf(m, f[e]);
    }
  }
#pragma unroll
  for (int off = 32; off > 0; off >>= 1) m = fmaxf(m, __shfl_down(m, off));
  if (lane == 0) wred[w] = m;
  __syncthreads();
  if (tid == 0) sm = fmaxf(fmaxf(wred[0], wred[1]), fmaxf(wred[2], wred[3]));
  __syncthreads();
  m = sm;

  float l = 0.f;
#pragma unroll
  for (int k = 0; k < 4; ++k) {
    const int j = tid + k * 256;
    if (j < nf4) {
      float* f = (float*)&v[k];
#pragma unroll
      for (int e = 0; e < 4; ++e) {
        const float p = (4 * j + e < valid) ? __expf(f[e] - m) : 0.f;
        f[e] = p;
        l += p;
      }
    }
  }
#pragma unroll
  for (int off = 32; off > 0; off >>= 1) l += __shfl_down(l, off);
  if (lane == 0) wred[w] = l;
  __syncthreads();
  if (tid == 0) sil = 1.f / (wred[0] + wred[1] + wred[2] + wred[3]);
  __syncthreads();
  const float il = sil;

#pragma unroll
  for (int k = 0; k < 4; ++k) {
    const int j = tid + k * 256;
    if (j < nf4) {
      const float* f = (const float*)&v[k];
      *(short4*)&prow[4 * j] = make_short4(f2bf(f[0] * il), f2bf(f[1] * il),
                                           f2bf(f[2] * il), f2bf(f[3] * il));
    }
  }
}

// ---------------------------------------------------------------------------
extern "C" void kernel_launch(void* const* d_in, const int* in_sizes, int n_in,
                              void* d_out, int out_size, void* d_ws,
                              size_t ws_size, hipStream_t stream) {
  (void)in_sizes; (void)n_in; (void)out_size; (void)ws_size;
  const float* x   = (const float*)d_in[0];
  const float* wqk = (const float*)d_in[1];
  const float* wov = (const float*)d_in[2];
  float* out = (float*)d_out;

  const size_t MB = 1ull << 20;
  char* p = (char*)d_ws;
  short* xh    = (short*)(p);             //  8 MB 4096x1024 bf16 hi
  short* xl    = (short*)(p + 8 * MB);    //  8 MB           bf16 lo
  short* wqkTh = (short*)(p + 16 * MB);   //  2 MB
  short* wqkTl = (short*)(p + 18 * MB);   //  2 MB
  short* wovT  = (short*)(p + 20 * MB);   //  2 MB
  short* qh    = (short*)(p + 22 * MB);   //  8 MB
  short* ql    = (short*)(p + 30 * MB);   //  8 MB
  short* vT    = (short*)(p + 38 * MB);   //  8 MB 1024x4096: vT[d][s]=(x@wov)[s][d]
  float* S     = (float*)(p + 46 * MB);   // 64 MB 4096x4096 fp32 (P aliases)
                                          // total 110 MB

  prep_all<<<4608, 256, 0, stream>>>(x, wqk, wov, xh, xl, wqkTh, wqkTl, wovT);
  // q = x @ wqk  (split-bf16 3-product, 128x64 tiles -> 512 blocks, 2/CU)
  mfma_nt<true, 2, 0, 64, 256, 2><<<dim3(16, 32), 256, 0, stream>>>(
      xh, xl, 1024, wqkTh, wqkTl, 1024, qh, ql, 1024, 0, 0, D_MODEL, 0);
  // fused: S = q @ x^T causal (528 blocks) + vT = (x@wov)^T (256 blocks)
  fused_qk_v<<<784, 256, 0, stream>>>(qh, ql, xh, xl, wovT, S, vT);
  // softmax rows -> P bf16 in place
  softmax_inplace<<<N_SEQ, 256, 0, stream>>>(S, 0);
  // out = P @ v  (bf16 -> fp32 out; 128x64 tiles, K-desc paired order)
  mfma_nt<false, 0, 2, 64, 512, 4><<<512, 512, 0, stream>>>(
      (const short*)S, nullptr, 8192, vT, nullptr, N_SEQ,
      out, nullptr, 1024, 0, 0, 128, 128);
}